// Round 9
// baseline (485.616 us; speedup 1.0000x reference)
//
#include <hip/hip_runtime.h>
#include <stdint.h>

#define D 128
#define BETA 0.40546510810816444f   // log(1.5)
#define TSTR 136                     // padded LDS row stride (bf16 elems)

#define NWG  128                     // legacy fallback bucket passes
#define MAXB 256                     // legacy: 512-row buckets, N <= 131072

#define NWG2 256                     // group/bhist workgroups (full machine)
#define BROWS 128                    // rows per bucket (782 place blocks at N=100K)
#define BSH   7                      // log2(BROWS)
#define MAXB2 1024                   // max buckets: N <= 131072

typedef __bf16 bf16x8 __attribute__((ext_vector_type(8)));
typedef float f32x4 __attribute__((ext_vector_type(4)));

__device__ __forceinline__ uint16_t f2bf(float f) {
    union { float f; uint32_t i; } x; x.f = f;
    uint32_t r = (x.i + 0x7fffu + ((x.i >> 16) & 1u)) >> 16;
    return (uint16_t)r;
}
__device__ __forceinline__ float lo_f(uint32_t u) { return __uint_as_float(u << 16); }
__device__ __forceinline__ float hi_f(uint32_t u) { return __uint_as_float(u & 0xffff0000u); }
__device__ __forceinline__ uint32_t pack2(float x, float y) {
    return (uint32_t)f2bf(x) | ((uint32_t)f2bf(y) << 16);
}

// ================= legacy CSR build (N > 131072 fallback) ==================
__global__ void k_hist(const int* __restrict__ row, int* __restrict__ deg, int E, int N) {
    int e = blockIdx.x * blockDim.x + threadIdx.x;
    if (e < E) {
        int r = row[e]; r = min(max(r, 0), N - 1);
        atomicAdd(&deg[r], 1);
    }
}

__global__ void k_scan1(const int* __restrict__ deg, int* __restrict__ inc,
                        int* __restrict__ bsum, int n) {
    __shared__ int s[1024];
    int i = blockIdx.x * 1024 + threadIdx.x;
    int v = (i < n) ? deg[i] : 0;
    s[threadIdx.x] = v;
    __syncthreads();
    for (int d = 1; d < 1024; d <<= 1) {
        int t = (threadIdx.x >= (unsigned)d) ? s[threadIdx.x - d] : 0;
        __syncthreads();
        s[threadIdx.x] += t;
        __syncthreads();
    }
    if (i < n) inc[i] = s[threadIdx.x];
    if (threadIdx.x == 1023) bsum[blockIdx.x] = s[1023];
}

__global__ void k_scan2(const int* __restrict__ bsum, int* __restrict__ boff,
                        int nb, int* __restrict__ rowptr, int N) {
    int run = 0;
    for (int b = 0; b < nb; b++) { boff[b] = run; run += bsum[b]; }
    rowptr[N] = run;
}

__global__ void k_scan3(const int* __restrict__ deg, const int* __restrict__ boff,
                        int* __restrict__ rowptr, int* __restrict__ wp, int n) {
    int i = blockIdx.x * 1024 + threadIdx.x;
    if (i < n) {
        int ex = rowptr[i] - deg[i] + boff[blockIdx.x];
        rowptr[i] = ex;
        wp[i] = ex;
    }
}

__global__ void k_scatter(const int* __restrict__ row, const int* __restrict__ col,
                          const float* __restrict__ vals, int* __restrict__ wp,
                          uint2* __restrict__ rec, int E, int N) {
    int e = blockIdx.x * blockDim.x + threadIdx.x;
    if (e < E) {
        int r = row[e]; r = min(max(r, 0), N - 1);
        int pos = atomicAdd(&wp[r], 1);
        pos = min(max(pos, 0), E - 1);
        uint2 rv;
        rv.x = (uint32_t)col[e];
        rv.y = __float_as_uint(vals[e]);
        rec[pos] = rv;
    }
}

// ======== standalone prep/cvt (fallback paths) ========
__global__ void k_cvt(const float4* __restrict__ src, uint2* __restrict__ dst, int n) {
    int i = blockIdx.x * blockDim.x + threadIdx.x;
    if (i < n) {
        float4 v = src[i];
        uint2 o; o.x = pack2(v.x, v.y); o.y = pack2(v.z, v.w);
        dst[i] = o;
    }
}

__global__ void k_prep(const float* __restrict__ W, const float* __restrict__ w1,
                       const float* __restrict__ w2, uint16_t* __restrict__ M1T,
                       uint16_t* __restrict__ M2T) {
    int k = blockIdx.x, n = threadIdx.x;
    __shared__ float imrow[D];
    imrow[n] = (1.0f - BETA) + BETA * W[k * D + n];
    __syncthreads();
    float s1 = 0.f, s2 = 0.f;
    for (int j = 0; j < D; j++) {
        float im = imrow[j];
        s1 += im * w1[j * D + n];
        s2 += im * w2[j * D + n];
    }
    M1T[n * D + k] = f2bf(s1);
    M2T[n * D + k] = f2bf(s2);
}

// ============ fused front: prep (0..63) + cvt + bhist (256 WGs) =============
__global__ __launch_bounds__(256) void k_front(
        const float* __restrict__ W, const float* __restrict__ w1,
        const float* __restrict__ w2, uint16_t* __restrict__ M1T,
        uint16_t* __restrict__ M2T,
        const float4* __restrict__ egoq, uint2* __restrict__ egobq, int nquads,
        const int* __restrict__ row, int* __restrict__ cnt,
        int E, int N, int nbuck, int cvtB) {
    __shared__ int h[MAXB2];
    __shared__ float imrow[2][D];
    int tid = threadIdx.x;
    int bid = blockIdx.x;

    if (bid < 64) {
        // ---- prep role: 2 k-rows per block ----
        int half = tid >> 7;
        int n = tid & 127;
        int k = bid * 2 + half;
        imrow[half][n] = (1.0f - BETA) + BETA * W[k * D + n];
        __syncthreads();
        float s1 = 0.f, s2 = 0.f;
        for (int j = 0; j < D; j++) {
            float im = imrow[half][j];
            s1 += im * w1[j * D + n];
            s2 += im * w2[j * D + n];
        }
        M1T[n * D + k] = f2bf(s1);
        M2T[n * D + k] = f2bf(s2);
        return;
    }
    if (bid < 64 + cvtB) {
        // ---- cvt role ----
        int i = (bid - 64) * 256 + tid;
        if (i < nquads) {
            float4 v = egoq[i];
            uint2 o; o.x = pack2(v.x, v.y); o.y = pack2(v.z, v.w);
            egobq[i] = o;
        }
        return;
    }
    // ---- bhist role (256 WGs, 128-row buckets) ----
    int w = bid - 64 - cvtB;
    for (int b = tid; b < nbuck; b += 256) h[b] = 0;
    __syncthreads();
    int chunk = (E + NWG2 - 1) / NWG2;
    int beg = w * chunk, end = min(beg + chunk, E);
    for (int e = beg + tid; e < end; e += 256) {
        int r = row[e]; r = min(max(r, 0), N - 1);
        atomicAdd(&h[r >> BSH], 1);
    }
    __syncthreads();
    for (int b = tid; b < nbuck; b += 256) cnt[b * NWG2 + w] = h[b];
}

// ============ group: 256 WGs x 512 thr; per-WG private bucket segments ======
// Prelude: every block redundantly computes the bucket-total exclusive scan
// (2 buckets/thread, nbuck <= 1024) from the L2-hot cnt matrix. Block 0
// publishes bbase for k_place2. lbase[b] = bb[b] + sum_{w'<w} cnt[b][w'].
// Record: x = (row & (BROWS-1)) << 17 | col (needs N <= 131072).
__global__ __launch_bounds__(512) void k_group2(const int* __restrict__ row,
                                                const int* __restrict__ col,
                                                const float* __restrict__ vals,
                                                const int* __restrict__ cnt,
                                                int* __restrict__ bbase,
                                                uint2* __restrict__ grouped,
                                                int E, int N, int nbuck) {
    __shared__ int s[512];
    __shared__ int bb[MAXB2 + 1];
    __shared__ int lbase[MAXB2];
    __shared__ int lcnt[MAXB2];
    int t = threadIdx.x;
    int w = blockIdx.x;

    // ---- bucket totals (2/thread) + 512-wide exclusive scan ----
    int t0 = 2 * t, t1v = 2 * t + 1;
    int totA = 0, totB = 0;
    if (t0 < nbuck) {
        const int4* p4 = (const int4*)(cnt + t0 * NWG2);
#pragma unroll 4
        for (int i2 = 0; i2 < NWG2 / 4; i2++) {
            int4 v = p4[i2];
            totA += v.x + v.y + v.z + v.w;
        }
    }
    if (t1v < nbuck) {
        const int4* p4 = (const int4*)(cnt + t1v * NWG2);
#pragma unroll 4
        for (int i2 = 0; i2 < NWG2 / 4; i2++) {
            int4 v = p4[i2];
            totB += v.x + v.y + v.z + v.w;
        }
    }
    s[t] = totA + totB;
    __syncthreads();
    for (int d = 1; d < 512; d <<= 1) {
        int x = (t >= d) ? s[t - d] : 0;
        __syncthreads();
        s[t] += x;
        __syncthreads();
    }
    int ex = s[t] - (totA + totB);
    if (t0 < nbuck) bb[t0] = ex;
    if (t1v < nbuck) bb[t1v] = ex + totA;
    if (t == 511) bb[nbuck] = s[511];
    __syncthreads();
    if (w == 0) {
        for (int b = t; b <= nbuck; b += 512) bbase[b] = bb[b];
    }

    // ---- per-WG private segment bases ----
    for (int b = t; b < nbuck; b += 512) {
        const int* cr = cnt + b * NWG2;
        int off = bb[b];
        for (int w2 = 0; w2 < w; w2++) off += cr[w2];
        lbase[b] = off;
        lcnt[b] = 0;
    }
    __syncthreads();
    int chunk = (E + NWG2 - 1) / NWG2;
    int beg = w * chunk, end = min(beg + chunk, E);
    for (int e = beg + t; e < end; e += 512) {
        int r = row[e]; r = min(max(r, 0), N - 1);
        int c = col[e]; c = min(max(c, 0), N - 1);
        int b = r >> BSH;
        int lp = atomicAdd(&lcnt[b], 1);
        int pos = lbase[b] + lp;
        pos = min(max(pos, 0), E - 1);
        uint2 g;
        g.x = ((uint32_t)(r & (BROWS - 1)) << 17) | (uint32_t)c;
        g.y = __float_as_uint(vals[e]);
        grouped[pos] = g;
    }
}

// ============ place: one block per 128-row bucket (~782 blocks) =============
__global__ __launch_bounds__(512) void k_place2(const uint2* __restrict__ grouped,
                                                const int* __restrict__ bbase,
                                                int* __restrict__ rowptr,
                                                uint2* __restrict__ rec,
                                                int E, int N, int nbuck) {
    __shared__ int lh[BROWS];
    __shared__ int lcc[BROWS];
    __shared__ int ps[BROWS];
    int b = blockIdx.x;
    int t = threadIdx.x;
    int pb = bbase[b], pe = bbase[b + 1];
    if (t < BROWS) { lh[t] = 0; lcc[t] = 0; }
    __syncthreads();
    for (int i = pb + t; i < pe; i += 512)
        atomicAdd(&lh[grouped[i].x >> 17], 1);
    __syncthreads();
    int v = (t < BROWS) ? lh[t] : 0;
    if (t < BROWS) ps[t] = v;
    __syncthreads();
    for (int d = 1; d < BROWS; d <<= 1) {
        int x = (t < BROWS && t >= d) ? ps[t - d] : 0;
        __syncthreads();
        if (t < BROWS) ps[t] += x;
        __syncthreads();
    }
    if (t < BROWS) lh[t] = ps[t] - v;           // exclusive row offsets
    __syncthreads();
    int rbase = b << BSH;
    if (t < BROWS) {
        int r = rbase + t;
        if (r < N) rowptr[r] = pb + lh[t];
    }
    if (b == nbuck - 1 && t == 0) rowptr[N] = E;
    for (int i = pb + t; i < pe; i += 512) {
        uint2 g = grouped[i];
        int rl = (int)(g.x >> 17);
        int lp = atomicAdd(&lcc[rl], 1);
        int pos = pb + lh[rl] + lp;
        pos = min(max(pos, 0), E - 1);
        uint2 rv; rv.x = g.x & 0x1FFFFu; rv.y = g.y;
        rec[pos] = rv;
    }
}

// ======== shared phase-2: dual MFMA GEMM + leaky-relu epilogue (f32 out) ====
__device__ __forceinline__ void gemm_phase(
        const uint16_t* sT1, const uint16_t* sT2,
        const uint16_t* __restrict__ M1T, const uint16_t* __restrict__ M2T,
        const float* __restrict__ b1, const float* __restrict__ b2,
        float* __restrict__ out, int base, int wave, int lane, int N) {
    int l15 = lane & 15, quad = lane >> 4;
#pragma unroll
    for (int t = 0; t < 2; t++) {
        int tn = wave * 2 + t;
        f32x4 acc1 = {0.f, 0.f, 0.f, 0.f}, acc2 = {0.f, 0.f, 0.f, 0.f};
#pragma unroll
        for (int kb = 0; kb < 4; kb++) {
            int ko = kb * 32 + quad * 8;
            bf16x8 a1 = *(const bf16x8*)(sT1 + l15 * TSTR + ko);
            bf16x8 a2 = *(const bf16x8*)(sT2 + l15 * TSTR + ko);
            bf16x8 bb1 = *(const bf16x8*)(M1T + (tn * 16 + l15) * D + ko);
            bf16x8 bb2 = *(const bf16x8*)(M2T + (tn * 16 + l15) * D + ko);
            acc1 = __builtin_amdgcn_mfma_f32_16x16x32_bf16(a1, bb1, acc1, 0, 0, 0);
            acc2 = __builtin_amdgcn_mfma_f32_16x16x32_bf16(a2, bb2, acc2, 0, 0, 0);
        }
        int colo = tn * 16 + l15;
        float bbias1 = b1[colo], bbias2 = b2[colo];
#pragma unroll
        for (int r = 0; r < 4; r++) {
            int rowi = base + quad * 4 + r;
            if (rowi < N) {
                float v1 = acc1[r] + bbias1;
                v1 = (v1 >= 0.f) ? v1 : 0.01f * v1;
                float v2 = acc2[r] + bbias2;
                v2 = (v2 >= 0.f) ? v2 : 0.01f * v2;
                out[(size_t)rowi * D + colo] = v1 + v2;   // FLOAT32 output
            }
        }
    }
}

// one 8-wide gather step for a row; e/e1 are wave-uniform (scalar path)
template<bool MASKED>
__device__ __forceinline__ void step8(const uint2* __restrict__ rec,
                                      const uint32_t* __restrict__ egob,
                                      int lane, int N, int e, int e1,
                                      float& ax, float& ay) {
    int last = e1 - 1;
    uint2 rr[8];
#pragma unroll
    for (int k = 0; k < 8; k++) {
        int idx = MASKED ? ((e + k <= last) ? e + k : last) : (e + k);
        rr[k] = rec[idx];
    }
    uint32_t uu[8];
#pragma unroll
    for (int k = 0; k < 8; k++) {
        int c = min(max((int)rr[k].x, 0), N - 1);
        uu[k] = egob[c * 64 + lane];
    }
#pragma unroll
    for (int k = 0; k < 8; k++) {
        float v = (!MASKED || (e + k < e1)) ? __uint_as_float(rr[k].y) : 0.f;
        ax += v * lo_f(uu[k]);
        ay += v * hi_f(uu[k]);
    }
}

// ======== fast path: dual-row scalar-record CSR gather -> LDS -> GEMM ========
// Records/rowptr are wave-uniform (readfirstlane -> s_load, SALU clamps,
// saddr gathers). Two adjacent rows interleaved in the main loop: 16
// outstanding 256B gathers per wave, cheap in VGPRs since records are SGPRs.
// b0 == a1 (adjacent CSR rows), so only 3 rowptr scalars per pair.
__global__ __launch_bounds__(256) void k_fused(
        const int* __restrict__ rowptr, const uint2* __restrict__ rec,
        const uint32_t* __restrict__ egob,
        const float2* __restrict__ egf, const float2* __restrict__ hh,
        const uint16_t* __restrict__ M1T, const uint16_t* __restrict__ M2T,
        const float* __restrict__ b1, const float* __restrict__ b2,
        float* __restrict__ out, int N) {
    __shared__ __attribute__((aligned(16))) uint16_t sT1[16 * TSTR];
    __shared__ __attribute__((aligned(16))) uint16_t sT2[16 * TSTR];
    int tid = threadIdx.x;
    int wave = tid >> 6, lane = tid & 63;
    int base = blockIdx.x * 16;
    uint32_t* s1d = (uint32_t*)sT1;
    uint32_t* s2d = (uint32_t*)sT2;

#pragma unroll
    for (int pi = 0; pi < 2; pi++) {
        int nodeA = __builtin_amdgcn_readfirstlane(base + wave * 4 + pi * 2);
        int nodeB = nodeA + 1;
        int a0 = 0, a1 = 0, b0 = 0, b1e = 0;
        if (nodeA < N) {
            a0 = rowptr[nodeA];
            a1 = rowptr[nodeA + 1];
            if (nodeB < N) { b0 = a1; b1e = rowptr[nodeB + 1]; }
        }
        float axA = 0.f, ayA = 0.f, axB = 0.f, ayB = 0.f;
        int eA = a0, eB = b0;
        // interleaved main: 16 outstanding gathers
        for (; eA + 8 <= a1 && eB + 8 <= b1e; eA += 8, eB += 8) {
            step8<false>(rec, egob, lane, N, eA, a1, axA, ayA);
            step8<false>(rec, egob, lane, N, eB, b1e, axB, ayB);
        }
        // A remainder
        for (; eA + 8 <= a1; eA += 8)
            step8<false>(rec, egob, lane, N, eA, a1, axA, ayA);
        if (eA < a1)
            step8<true>(rec, egob, lane, N, eA, a1, axA, ayA);
        // B remainder
        for (; eB + 8 <= b1e; eB += 8)
            step8<false>(rec, egob, lane, N, eB, b1e, axB, ayB);
        if (eB < b1e)
            step8<true>(rec, egob, lane, N, eB, b1e, axB, ayB);
        // blend + LDS store (A)
        {
            float t1x = 0.f, t1y = 0.f, t2x = 0.f, t2y = 0.f;
            if (nodeA < N) {
                float2 se = egf[nodeA * 64 + lane];
                float2 sh = hh[nodeA * 64 + lane];
                t1x = 0.9f * (se.x + axA) + 0.1f * sh.x;
                t1y = 0.9f * (se.y + ayA) + 0.1f * sh.y;
                t2x = 0.9f * (se.x * axA) + 0.1f * sh.x;
                t2y = 0.9f * (se.y * ayA) + 0.1f * sh.y;
            }
            int r = wave * 4 + pi * 2;
            s1d[r * (TSTR / 2) + lane] = pack2(t1x, t1y);
            s2d[r * (TSTR / 2) + lane] = pack2(t2x, t2y);
        }
        // blend + LDS store (B)
        {
            float t1x = 0.f, t1y = 0.f, t2x = 0.f, t2y = 0.f;
            if (nodeB < N) {
                float2 se = egf[nodeB * 64 + lane];
                float2 sh = hh[nodeB * 64 + lane];
                t1x = 0.9f * (se.x + axB) + 0.1f * sh.x;
                t1y = 0.9f * (se.y + ayB) + 0.1f * sh.y;
                t2x = 0.9f * (se.x * axB) + 0.1f * sh.x;
                t2y = 0.9f * (se.y * ayB) + 0.1f * sh.y;
            }
            int r = wave * 4 + pi * 2 + 1;
            s1d[r * (TSTR / 2) + lane] = pack2(t1x, t1y);
            s2d[r * (TSTR / 2) + lane] = pack2(t2x, t2y);
        }
    }
    __syncthreads();
    gemm_phase(sT1, sT2, M1T, M2T, b1, b2, out, base, wave, lane, N);
}

// ======== fallback path (tiny ws): f32 side accumulated in-place in d_out ====
__global__ __launch_bounds__(256) void k_coo_side(
        const int* __restrict__ row, const int* __restrict__ col,
        const float* __restrict__ vals, const float2* __restrict__ egf,
        float* __restrict__ sideF, int E, int N) {
    long long t = (long long)blockIdx.x * blockDim.x + threadIdx.x;
    int e = (int)(t >> 6), l = (int)(t & 63);
    if (e >= E) return;
    int c = col[e]; c = min(max(c, 0), N - 1);
    int r = row[e]; r = min(max(r, 0), N - 1);
    float v = vals[e];
    float2 u = egf[c * 64 + l];
    atomicAdd(&sideF[r * D + 2 * l],     v * u.x);
    atomicAdd(&sideF[r * D + 2 * l + 1], v * u.y);
}

__global__ __launch_bounds__(256) void k_fused2(
        const float2* __restrict__ egf, const float2* __restrict__ hh,
        const uint16_t* __restrict__ M1T, const uint16_t* __restrict__ M2T,
        const float* __restrict__ b1, const float* __restrict__ b2,
        float* __restrict__ out, int N) {
    __shared__ __attribute__((aligned(16))) uint16_t sT1[16 * TSTR];
    __shared__ __attribute__((aligned(16))) uint16_t sT2[16 * TSTR];
    int tid = threadIdx.x;
    int wave = tid >> 6, lane = tid & 63;
    int base = blockIdx.x * 16;
    const float2* sd = (const float2*)out;
    uint32_t* s1d = (uint32_t*)sT1;
    uint32_t* s2d = (uint32_t*)sT2;

#pragma unroll
    for (int i = 0; i < 4; i++) {
        int node = base + wave * 4 + i;
        float t1x = 0.f, t1y = 0.f, t2x = 0.f, t2y = 0.f;
        if (node < N) {
            float2 us = sd[node * 64 + lane];
            float2 se = egf[node * 64 + lane];
            float2 sh = hh[node * 64 + lane];
            t1x = 0.9f * (se.x + us.x) + 0.1f * sh.x;
            t1y = 0.9f * (se.y + us.y) + 0.1f * sh.y;
            t2x = 0.9f * (se.x * us.x) + 0.1f * sh.x;
            t2y = 0.9f * (se.y * us.y) + 0.1f * sh.y;
        }
        int r = wave * 4 + i;
        s1d[r * (TSTR / 2) + lane] = pack2(t1x, t1y);
        s2d[r * (TSTR / 2) + lane] = pack2(t2x, t2y);
    }
    __syncthreads();
    gemm_phase(sT1, sT2, M1T, M2T, b1, b2, out, base, wave, lane, N);
}

extern "C" void kernel_launch(void* const* d_in, const int* in_sizes, int n_in,
                              void* d_out, int out_size, void* d_ws, size_t ws_size,
                              hipStream_t stream) {
    const float* ego  = (const float*)d_in[0];
    const float* h0   = (const float*)d_in[1];
    const float* vals = (const float*)d_in[2];
    const float* W    = (const float*)d_in[3];
    const float* w1   = (const float*)d_in[4];
    const float* b1   = (const float*)d_in[5];
    const float* w2   = (const float*)d_in[6];
    const float* b2   = (const float*)d_in[7];
    const int* row = (const int*)d_in[8];
    const int* col = (const int*)d_in[9];
    int N = in_sizes[0] / D;
    int E = in_sizes[2];

    int nbuck2 = (N + BROWS - 1) >> BSH;          // 128-row buckets
    size_t cnt_elems = (size_t)nbuck2 * NWG2 + 2;
    if (cnt_elems < (size_t)MAXB * NWG + 1) cnt_elems = (size_t)MAXB * NWG + 1;

    char* p = (char*)d_ws;
    auto alloc = [&](size_t bytes) -> char* {
        char* q = p;
        p += (bytes + 511) & ~(size_t)511;
        return q;
    };
    uint16_t* M1T    = (uint16_t*)alloc(D * D * 2);
    uint16_t* M2T    = (uint16_t*)alloc(D * D * 2);
    uint32_t* egob   = (uint32_t*)alloc((size_t)N * 64 * 4);
    int*      deg    = (int*)alloc((size_t)N * 4);
    int*      rowptr = (int*)alloc((size_t)(N + 1) * 4);
    int*      wp     = (int*)alloc((size_t)N * 4);
    int*      bsum   = (int*)alloc(1024 * 4);
    int*      boff   = (int*)alloc((MAXB2 + 2) * 4);   // bbase (<= 1025 ints)
    int*      cnt    = (int*)alloc(cnt_elems * 4);
    uint2*    rec    = (uint2*)alloc((size_t)E * 8);
    size_t need_fast = (size_t)(p - (char*)d_ws);

    if (ws_size >= need_fast) {
        int nquads = N * 32;
        bool bucket_ok = (nbuck2 <= MAXB2) && ((size_t)out_size * 4 >= (size_t)E * 8);
        if (bucket_ok) {
            // -- 3-dispatch bucketed build: front -> group(+scan) -> place --
            int cvtB = (nquads + 255) / 256;
            k_front<<<64 + cvtB + NWG2, 256, 0, stream>>>(
                W, w1, w2, M1T, M2T,
                (const float4*)ego, (uint2*)egob, nquads,
                row, cnt, E, N, nbuck2, cvtB);
            k_group2<<<NWG2, 512, 0, stream>>>(row, col, vals, cnt, boff,
                                               (uint2*)d_out, E, N, nbuck2);
            k_place2<<<nbuck2, 512, 0, stream>>>((const uint2*)d_out, boff,
                                                 rowptr, rec, E, N, nbuck2);
        } else {
            // -- legacy atomic scatter (handles N > 131072) --
            k_prep<<<D, D, 0, stream>>>(W, w1, w2, M1T, M2T);
            k_cvt<<<(nquads + 255) / 256, 256, 0, stream>>>((const float4*)ego,
                                                            (uint2*)egob, nquads);
            hipMemsetAsync(deg, 0, (size_t)N * 4, stream);
            int nb = (N + 1023) / 1024;
            k_hist<<<(E + 255) / 256, 256, 0, stream>>>(row, deg, E, N);
            k_scan1<<<nb, 1024, 0, stream>>>(deg, rowptr, bsum, N);
            k_scan2<<<1, 1, 0, stream>>>(bsum, boff, nb, rowptr, N);
            k_scan3<<<nb, 1024, 0, stream>>>(deg, boff, rowptr, wp, N);
            k_scatter<<<(E + 255) / 256, 256, 0, stream>>>(row, col, vals, wp,
                                                           rec, E, N);
        }
        int nblocks = (N + 15) / 16;
        k_fused<<<nblocks, 256, 0, stream>>>(rowptr, rec, egob,
                                             (const float2*)ego, (const float2*)h0,
                                             M1T, M2T, b1, b2, (float*)d_out, N);
    } else {
        k_prep<<<D, D, 0, stream>>>(W, w1, w2, M1T, M2T);
        hipMemsetAsync(d_out, 0, (size_t)out_size * 4, stream);
        long long tthr = (long long)E * 64;
        int blocks = (int)((tthr + 255) / 256);
        k_coo_side<<<blocks, 256, 0, stream>>>(row, col, vals, (const float2*)ego,
                                               (float*)d_out, E, N);
        int nblocks = (N + 15) / 16;
        k_fused2<<<nblocks, 256, 0, stream>>>((const float2*)ego, (const float2*)h0,
                                              M1T, M2T, b1, b2, (float*)d_out, N);
    }
}

// Round 10
// 445.114 us; speedup vs baseline: 1.0910x; 1.0910x over previous
//
#include <hip/hip_runtime.h>
#include <stdint.h>

#define D 128
#define BETA 0.40546510810816444f   // log(1.5)
#define TSTR 136                     // padded LDS row stride (bf16 elems)

#define NWG  128                     // legacy fallback bucket passes
#define MAXB 256                     // legacy: 512-row buckets, N <= 131072

#define NWG2 256                     // group/bhist workgroups (full machine)
#define BROWS 256                    // rows per bucket (391 place blocks at N=100K)
#define BSH   8                      // log2(BROWS)
#define MAXB2 512                    // max buckets: N <= 131072

typedef __bf16 bf16x8 __attribute__((ext_vector_type(8)));
typedef float f32x4 __attribute__((ext_vector_type(4)));

__device__ __forceinline__ uint16_t f2bf(float f) {
    union { float f; uint32_t i; } x; x.f = f;
    uint32_t r = (x.i + 0x7fffu + ((x.i >> 16) & 1u)) >> 16;
    return (uint16_t)r;
}
__device__ __forceinline__ float lo_f(uint32_t u) { return __uint_as_float(u << 16); }
__device__ __forceinline__ float hi_f(uint32_t u) { return __uint_as_float(u & 0xffff0000u); }
__device__ __forceinline__ uint32_t pack2(float x, float y) {
    return (uint32_t)f2bf(x) | ((uint32_t)f2bf(y) << 16);
}

// ================= legacy CSR build (N > 131072 fallback) ==================
__global__ void k_hist(const int* __restrict__ row, int* __restrict__ deg, int E, int N) {
    int e = blockIdx.x * blockDim.x + threadIdx.x;
    if (e < E) {
        int r = row[e]; r = min(max(r, 0), N - 1);
        atomicAdd(&deg[r], 1);
    }
}

__global__ void k_scan1(const int* __restrict__ deg, int* __restrict__ inc,
                        int* __restrict__ bsum, int n) {
    __shared__ int s[1024];
    int i = blockIdx.x * 1024 + threadIdx.x;
    int v = (i < n) ? deg[i] : 0;
    s[threadIdx.x] = v;
    __syncthreads();
    for (int d = 1; d < 1024; d <<= 1) {
        int t = (threadIdx.x >= (unsigned)d) ? s[threadIdx.x - d] : 0;
        __syncthreads();
        s[threadIdx.x] += t;
        __syncthreads();
    }
    if (i < n) inc[i] = s[threadIdx.x];
    if (threadIdx.x == 1023) bsum[blockIdx.x] = s[1023];
}

__global__ void k_scan2(const int* __restrict__ bsum, int* __restrict__ boff,
                        int nb, int* __restrict__ rowptr, int N) {
    int run = 0;
    for (int b = 0; b < nb; b++) { boff[b] = run; run += bsum[b]; }
    rowptr[N] = run;
}

__global__ void k_scan3(const int* __restrict__ deg, const int* __restrict__ boff,
                        int* __restrict__ rowptr, int* __restrict__ wp, int n) {
    int i = blockIdx.x * 1024 + threadIdx.x;
    if (i < n) {
        int ex = rowptr[i] - deg[i] + boff[blockIdx.x];
        rowptr[i] = ex;
        wp[i] = ex;
    }
}

__global__ void k_scatter(const int* __restrict__ row, const int* __restrict__ col,
                          const float* __restrict__ vals, int* __restrict__ wp,
                          uint2* __restrict__ rec, int E, int N) {
    int e = blockIdx.x * blockDim.x + threadIdx.x;
    if (e < E) {
        int r = row[e]; r = min(max(r, 0), N - 1);
        int pos = atomicAdd(&wp[r], 1);
        pos = min(max(pos, 0), E - 1);
        uint2 rv;
        rv.x = (uint32_t)col[e];
        rv.y = __float_as_uint(vals[e]);
        rec[pos] = rv;
    }
}

// ======== standalone prep/cvt (fallback paths) ========
__global__ void k_cvt(const float4* __restrict__ src, uint2* __restrict__ dst, int n) {
    int i = blockIdx.x * blockDim.x + threadIdx.x;
    if (i < n) {
        float4 v = src[i];
        uint2 o; o.x = pack2(v.x, v.y); o.y = pack2(v.z, v.w);
        dst[i] = o;
    }
}

__global__ void k_prep(const float* __restrict__ W, const float* __restrict__ w1,
                       const float* __restrict__ w2, uint16_t* __restrict__ M1T,
                       uint16_t* __restrict__ M2T) {
    int k = blockIdx.x, n = threadIdx.x;
    __shared__ float imrow[D];
    imrow[n] = (1.0f - BETA) + BETA * W[k * D + n];
    __syncthreads();
    float s1 = 0.f, s2 = 0.f;
    for (int j = 0; j < D; j++) {
        float im = imrow[j];
        s1 += im * w1[j * D + n];
        s2 += im * w2[j * D + n];
    }
    M1T[n * D + k] = f2bf(s1);
    M2T[n * D + k] = f2bf(s2);
}

// ============ fused front: prep (0..63) + cvt + bhist (256 WGs) =============
__global__ __launch_bounds__(256) void k_front(
        const float* __restrict__ W, const float* __restrict__ w1,
        const float* __restrict__ w2, uint16_t* __restrict__ M1T,
        uint16_t* __restrict__ M2T,
        const float4* __restrict__ egoq, uint2* __restrict__ egobq, int nquads,
        const int* __restrict__ row, int* __restrict__ cnt,
        int E, int N, int nbuck, int cvtB) {
    __shared__ int h[MAXB2];
    __shared__ float imrow[2][D];
    int tid = threadIdx.x;
    int bid = blockIdx.x;

    if (bid < 64) {
        // ---- prep role: 2 k-rows per block ----
        int half = tid >> 7;
        int n = tid & 127;
        int k = bid * 2 + half;
        imrow[half][n] = (1.0f - BETA) + BETA * W[k * D + n];
        __syncthreads();
        float s1 = 0.f, s2 = 0.f;
        for (int j = 0; j < D; j++) {
            float im = imrow[half][j];
            s1 += im * w1[j * D + n];
            s2 += im * w2[j * D + n];
        }
        M1T[n * D + k] = f2bf(s1);
        M2T[n * D + k] = f2bf(s2);
        return;
    }
    if (bid < 64 + cvtB) {
        // ---- cvt role ----
        int i = (bid - 64) * 256 + tid;
        if (i < nquads) {
            float4 v = egoq[i];
            uint2 o; o.x = pack2(v.x, v.y); o.y = pack2(v.z, v.w);
            egobq[i] = o;
        }
        return;
    }
    // ---- bhist role (256 WGs, 256-row buckets) ----
    int w = bid - 64 - cvtB;
    for (int b = tid; b < nbuck; b += 256) h[b] = 0;
    __syncthreads();
    int chunk = (E + NWG2 - 1) / NWG2;
    int beg = w * chunk, end = min(beg + chunk, E);
    for (int e = beg + tid; e < end; e += 256) {
        int r = row[e]; r = min(max(r, 0), N - 1);
        atomicAdd(&h[r >> BSH], 1);
    }
    __syncthreads();
    for (int b = tid; b < nbuck; b += 256) cnt[b * NWG2 + w] = h[b];
}

// ============ group: 256 WGs x 512 thr; per-WG private bucket segments ======
// Prelude: every block redundantly computes the bucket-total exclusive scan
// from the L2-hot cnt matrix (deterministic across blocks). Block 0 publishes
// bbase for k_place2. lbase[b] = bb[b] + sum_{w'<w} cnt[b][w'].
// Record: x = (row & 255) << 17 | col (needs N <= 131072).
__global__ __launch_bounds__(512) void k_group2(const int* __restrict__ row,
                                                const int* __restrict__ col,
                                                const float* __restrict__ vals,
                                                const int* __restrict__ cnt,
                                                int* __restrict__ bbase,
                                                uint2* __restrict__ grouped,
                                                int E, int N, int nbuck) {
    __shared__ int s[512];
    __shared__ int bb[MAXB2 + 1];
    __shared__ int lbase[MAXB2];
    __shared__ int lcnt[MAXB2];
    int t = threadIdx.x;
    int w = blockIdx.x;

    // ---- bucket totals + 512-wide exclusive scan ----
    int tot = 0;
    if (t < nbuck) {
        const int4* p4 = (const int4*)(cnt + t * NWG2);
#pragma unroll 4
        for (int i2 = 0; i2 < NWG2 / 4; i2++) {
            int4 v = p4[i2];
            tot += v.x + v.y + v.z + v.w;
        }
    }
    s[t] = tot;
    __syncthreads();
    for (int d = 1; d < 512; d <<= 1) {
        int x = (t >= d) ? s[t - d] : 0;
        __syncthreads();
        s[t] += x;
        __syncthreads();
    }
    if (t < nbuck) bb[t] = s[t] - tot;
    if (t == 511) bb[nbuck] = s[511];
    __syncthreads();
    if (w == 0) {
        for (int b = t; b <= nbuck; b += 512) bbase[b] = bb[b];
    }

    // ---- per-WG private segment bases ----
    for (int b = t; b < nbuck; b += 512) {
        const int* cr = cnt + b * NWG2;
        int off = bb[b];
        for (int w2 = 0; w2 < w; w2++) off += cr[w2];
        lbase[b] = off;
        lcnt[b] = 0;
    }
    __syncthreads();
    int chunk = (E + NWG2 - 1) / NWG2;
    int beg = w * chunk, end = min(beg + chunk, E);
    for (int e = beg + t; e < end; e += 512) {
        int r = row[e]; r = min(max(r, 0), N - 1);
        int c = col[e]; c = min(max(c, 0), N - 1);
        int b = r >> BSH;
        int lp = atomicAdd(&lcnt[b], 1);
        int pos = lbase[b] + lp;
        pos = min(max(pos, 0), E - 1);
        uint2 g;
        g.x = ((uint32_t)(r & (BROWS - 1)) << 17) | (uint32_t)c;
        g.y = __float_as_uint(vals[e]);
        grouped[pos] = g;
    }
}

// ============ place: one block per 256-row bucket (~391 blocks) =============
__global__ __launch_bounds__(512) void k_place2(const uint2* __restrict__ grouped,
                                                const int* __restrict__ bbase,
                                                int* __restrict__ rowptr,
                                                uint2* __restrict__ rec,
                                                int E, int N, int nbuck) {
    __shared__ int lh[BROWS];
    __shared__ int lcc[BROWS];
    __shared__ int ps[BROWS];
    int b = blockIdx.x;
    int t = threadIdx.x;
    int pb = bbase[b], pe = bbase[b + 1];
    if (t < BROWS) { lh[t] = 0; lcc[t] = 0; }
    __syncthreads();
    for (int i = pb + t; i < pe; i += 512)
        atomicAdd(&lh[grouped[i].x >> 17], 1);
    __syncthreads();
    int v = (t < BROWS) ? lh[t] : 0;
    if (t < BROWS) ps[t] = v;
    __syncthreads();
    for (int d = 1; d < BROWS; d <<= 1) {
        int x = (t < BROWS && t >= d) ? ps[t - d] : 0;
        __syncthreads();
        if (t < BROWS) ps[t] += x;
        __syncthreads();
    }
    if (t < BROWS) lh[t] = ps[t] - v;           // exclusive row offsets
    __syncthreads();
    int rbase = b << BSH;
    if (t < BROWS) {
        int r = rbase + t;
        if (r < N) rowptr[r] = pb + lh[t];
    }
    if (b == nbuck - 1 && t == 0) rowptr[N] = E;
    for (int i = pb + t; i < pe; i += 512) {
        uint2 g = grouped[i];
        int rl = (int)(g.x >> 17);
        int lp = atomicAdd(&lcc[rl], 1);
        int pos = pb + lh[rl] + lp;
        pos = min(max(pos, 0), E - 1);
        uint2 rv; rv.x = g.x & 0x1FFFFu; rv.y = g.y;
        rec[pos] = rv;
    }
}

// ======== shared phase-2: dual MFMA GEMM + leaky-relu epilogue (f32 out) ====
__device__ __forceinline__ void gemm_phase(
        const uint16_t* sT1, const uint16_t* sT2,
        const uint16_t* __restrict__ M1T, const uint16_t* __restrict__ M2T,
        const float* __restrict__ b1, const float* __restrict__ b2,
        float* __restrict__ out, int base, int wave, int lane, int N) {
    int l15 = lane & 15, quad = lane >> 4;
#pragma unroll
    for (int t = 0; t < 2; t++) {
        int tn = wave * 2 + t;
        f32x4 acc1 = {0.f, 0.f, 0.f, 0.f}, acc2 = {0.f, 0.f, 0.f, 0.f};
#pragma unroll
        for (int kb = 0; kb < 4; kb++) {
            int ko = kb * 32 + quad * 8;
            bf16x8 a1 = *(const bf16x8*)(sT1 + l15 * TSTR + ko);
            bf16x8 a2 = *(const bf16x8*)(sT2 + l15 * TSTR + ko);
            bf16x8 bb1 = *(const bf16x8*)(M1T + (tn * 16 + l15) * D + ko);
            bf16x8 bb2 = *(const bf16x8*)(M2T + (tn * 16 + l15) * D + ko);
            acc1 = __builtin_amdgcn_mfma_f32_16x16x32_bf16(a1, bb1, acc1, 0, 0, 0);
            acc2 = __builtin_amdgcn_mfma_f32_16x16x32_bf16(a2, bb2, acc2, 0, 0, 0);
        }
        int colo = tn * 16 + l15;
        float bbias1 = b1[colo], bbias2 = b2[colo];
#pragma unroll
        for (int r = 0; r < 4; r++) {
            int rowi = base + quad * 4 + r;
            if (rowi < N) {
                float v1 = acc1[r] + bbias1;
                v1 = (v1 >= 0.f) ? v1 : 0.01f * v1;
                float v2 = acc2[r] + bbias2;
                v2 = (v2 >= 0.f) ? v2 : 0.01f * v2;
                out[(size_t)rowi * D + colo] = v1 + v2;   // FLOAT32 output
            }
        }
    }
}

// one 8-wide gather step for a row; e/e1 are wave-uniform (scalar path)
template<bool MASKED>
__device__ __forceinline__ void step8(const uint2* __restrict__ rec,
                                      const uint32_t* __restrict__ egob,
                                      int lane, int N, int e, int e1,
                                      float& ax, float& ay) {
    int last = e1 - 1;
    uint2 rr[8];
#pragma unroll
    for (int k = 0; k < 8; k++) {
        int idx = MASKED ? ((e + k <= last) ? e + k : last) : (e + k);
        rr[k] = rec[idx];
    }
    uint32_t uu[8];
#pragma unroll
    for (int k = 0; k < 8; k++) {
        int c = min(max((int)rr[k].x, 0), N - 1);
        uu[k] = egob[c * 64 + lane];
    }
#pragma unroll
    for (int k = 0; k < 8; k++) {
        float v = (!MASKED || (e + k < e1)) ? __uint_as_float(rr[k].y) : 0.f;
        ax += v * lo_f(uu[k]);
        ay += v * hi_f(uu[k]);
    }
}

// ======== fast path: dual-row scalar-record CSR gather -> LDS -> GEMM ========
// Records/rowptr are wave-uniform (readfirstlane -> s_load, SALU clamps,
// saddr gathers). Two adjacent rows interleaved in the main loop: 16
// outstanding 256B gathers per wave, cheap in VGPRs since records are SGPRs.
__global__ __launch_bounds__(256) void k_fused(
        const int* __restrict__ rowptr, const uint2* __restrict__ rec,
        const uint32_t* __restrict__ egob,
        const float2* __restrict__ egf, const float2* __restrict__ hh,
        const uint16_t* __restrict__ M1T, const uint16_t* __restrict__ M2T,
        const float* __restrict__ b1, const float* __restrict__ b2,
        float* __restrict__ out, int N) {
    __shared__ __attribute__((aligned(16))) uint16_t sT1[16 * TSTR];
    __shared__ __attribute__((aligned(16))) uint16_t sT2[16 * TSTR];
    int tid = threadIdx.x;
    int wave = tid >> 6, lane = tid & 63;
    int base = blockIdx.x * 16;
    uint32_t* s1d = (uint32_t*)sT1;
    uint32_t* s2d = (uint32_t*)sT2;

#pragma unroll
    for (int pi = 0; pi < 2; pi++) {
        int nodeA = __builtin_amdgcn_readfirstlane(base + wave * 4 + pi * 2);
        int nodeB = nodeA + 1;
        int a0 = 0, a1 = 0, b0 = 0, b1e = 0;
        if (nodeA < N) {
            a0 = rowptr[nodeA];
            a1 = rowptr[nodeA + 1];
            if (nodeB < N) { b0 = a1; b1e = rowptr[nodeB + 1]; }
        }
        float axA = 0.f, ayA = 0.f, axB = 0.f, ayB = 0.f;
        int eA = a0, eB = b0;
        // interleaved main: 16 outstanding gathers
        for (; eA + 8 <= a1 && eB + 8 <= b1e; eA += 8, eB += 8) {
            step8<false>(rec, egob, lane, N, eA, a1, axA, ayA);
            step8<false>(rec, egob, lane, N, eB, b1e, axB, ayB);
        }
        // A remainder
        for (; eA + 8 <= a1; eA += 8)
            step8<false>(rec, egob, lane, N, eA, a1, axA, ayA);
        if (eA < a1)
            step8<true>(rec, egob, lane, N, eA, a1, axA, ayA);
        // B remainder
        for (; eB + 8 <= b1e; eB += 8)
            step8<false>(rec, egob, lane, N, eB, b1e, axB, ayB);
        if (eB < b1e)
            step8<true>(rec, egob, lane, N, eB, b1e, axB, ayB);
        // blend + LDS store (A)
        {
            float t1x = 0.f, t1y = 0.f, t2x = 0.f, t2y = 0.f;
            if (nodeA < N) {
                float2 se = egf[nodeA * 64 + lane];
                float2 sh = hh[nodeA * 64 + lane];
                t1x = 0.9f * (se.x + axA) + 0.1f * sh.x;
                t1y = 0.9f * (se.y + ayA) + 0.1f * sh.y;
                t2x = 0.9f * (se.x * axA) + 0.1f * sh.x;
                t2y = 0.9f * (se.y * ayA) + 0.1f * sh.y;
            }
            int r = wave * 4 + pi * 2;
            s1d[r * (TSTR / 2) + lane] = pack2(t1x, t1y);
            s2d[r * (TSTR / 2) + lane] = pack2(t2x, t2y);
        }
        // blend + LDS store (B)
        {
            float t1x = 0.f, t1y = 0.f, t2x = 0.f, t2y = 0.f;
            if (nodeB < N) {
                float2 se = egf[nodeB * 64 + lane];
                float2 sh = hh[nodeB * 64 + lane];
                t1x = 0.9f * (se.x + axB) + 0.1f * sh.x;
                t1y = 0.9f * (se.y + ayB) + 0.1f * sh.y;
                t2x = 0.9f * (se.x * axB) + 0.1f * sh.x;
                t2y = 0.9f * (se.y * ayB) + 0.1f * sh.y;
            }
            int r = wave * 4 + pi * 2 + 1;
            s1d[r * (TSTR / 2) + lane] = pack2(t1x, t1y);
            s2d[r * (TSTR / 2) + lane] = pack2(t2x, t2y);
        }
    }
    __syncthreads();
    gemm_phase(sT1, sT2, M1T, M2T, b1, b2, out, base, wave, lane, N);
}

// ======== fallback path (tiny ws): f32 side accumulated in-place in d_out ====
__global__ __launch_bounds__(256) void k_coo_side(
        const int* __restrict__ row, const int* __restrict__ col,
        const float* __restrict__ vals, const float2* __restrict__ egf,
        float* __restrict__ sideF, int E, int N) {
    long long t = (long long)blockIdx.x * blockDim.x + threadIdx.x;
    int e = (int)(t >> 6), l = (int)(t & 63);
    if (e >= E) return;
    int c = col[e]; c = min(max(c, 0), N - 1);
    int r = row[e]; r = min(max(r, 0), N - 1);
    float v = vals[e];
    float2 u = egf[c * 64 + l];
    atomicAdd(&sideF[r * D + 2 * l],     v * u.x);
    atomicAdd(&sideF[r * D + 2 * l + 1], v * u.y);
}

__global__ __launch_bounds__(256) void k_fused2(
        const float2* __restrict__ egf, const float2* __restrict__ hh,
        const uint16_t* __restrict__ M1T, const uint16_t* __restrict__ M2T,
        const float* __restrict__ b1, const float* __restrict__ b2,
        float* __restrict__ out, int N) {
    __shared__ __attribute__((aligned(16))) uint16_t sT1[16 * TSTR];
    __shared__ __attribute__((aligned(16))) uint16_t sT2[16 * TSTR];
    int tid = threadIdx.x;
    int wave = tid >> 6, lane = tid & 63;
    int base = blockIdx.x * 16;
    const float2* sd = (const float2*)out;
    uint32_t* s1d = (uint32_t*)sT1;
    uint32_t* s2d = (uint32_t*)sT2;

#pragma unroll
    for (int i = 0; i < 4; i++) {
        int node = base + wave * 4 + i;
        float t1x = 0.f, t1y = 0.f, t2x = 0.f, t2y = 0.f;
        if (node < N) {
            float2 us = sd[node * 64 + lane];
            float2 se = egf[node * 64 + lane];
            float2 sh = hh[node * 64 + lane];
            t1x = 0.9f * (se.x + us.x) + 0.1f * sh.x;
            t1y = 0.9f * (se.y + us.y) + 0.1f * sh.y;
            t2x = 0.9f * (se.x * us.x) + 0.1f * sh.x;
            t2y = 0.9f * (se.y * us.y) + 0.1f * sh.y;
        }
        int r = wave * 4 + i;
        s1d[r * (TSTR / 2) + lane] = pack2(t1x, t1y);
        s2d[r * (TSTR / 2) + lane] = pack2(t2x, t2y);
    }
    __syncthreads();
    gemm_phase(sT1, sT2, M1T, M2T, b1, b2, out, base, wave, lane, N);
}

extern "C" void kernel_launch(void* const* d_in, const int* in_sizes, int n_in,
                              void* d_out, int out_size, void* d_ws, size_t ws_size,
                              hipStream_t stream) {
    const float* ego  = (const float*)d_in[0];
    const float* h0   = (const float*)d_in[1];
    const float* vals = (const float*)d_in[2];
    const float* W    = (const float*)d_in[3];
    const float* w1   = (const float*)d_in[4];
    const float* b1   = (const float*)d_in[5];
    const float* w2   = (const float*)d_in[6];
    const float* b2   = (const float*)d_in[7];
    const int* row = (const int*)d_in[8];
    const int* col = (const int*)d_in[9];
    int N = in_sizes[0] / D;
    int E = in_sizes[2];

    int nbuck2 = (N + BROWS - 1) >> BSH;          // 256-row buckets
    size_t cnt_elems = (size_t)nbuck2 * NWG2 + 2;
    if (cnt_elems < (size_t)MAXB * NWG + 1) cnt_elems = (size_t)MAXB * NWG + 1;

    char* p = (char*)d_ws;
    auto alloc = [&](size_t bytes) -> char* {
        char* q = p;
        p += (bytes + 511) & ~(size_t)511;
        return q;
    };
    uint16_t* M1T    = (uint16_t*)alloc(D * D * 2);
    uint16_t* M2T    = (uint16_t*)alloc(D * D * 2);
    uint32_t* egob   = (uint32_t*)alloc((size_t)N * 64 * 4);
    int*      deg    = (int*)alloc((size_t)N * 4);
    int*      rowptr = (int*)alloc((size_t)(N + 1) * 4);
    int*      wp     = (int*)alloc((size_t)N * 4);
    int*      bsum   = (int*)alloc(1024 * 4);
    int*      boff   = (int*)alloc((MAXB2 + 2) * 4);   // bbase (<= 513 ints)
    int*      cnt    = (int*)alloc(cnt_elems * 4);
    uint2*    rec    = (uint2*)alloc((size_t)E * 8);
    size_t need_fast = (size_t)(p - (char*)d_ws);

    if (ws_size >= need_fast) {
        int nquads = N * 32;
        bool bucket_ok = (nbuck2 <= MAXB2) && ((size_t)out_size * 4 >= (size_t)E * 8);
        if (bucket_ok) {
            // -- 3-dispatch bucketed build: front -> group(+scan) -> place --
            int cvtB = (nquads + 255) / 256;
            k_front<<<64 + cvtB + NWG2, 256, 0, stream>>>(
                W, w1, w2, M1T, M2T,
                (const float4*)ego, (uint2*)egob, nquads,
                row, cnt, E, N, nbuck2, cvtB);
            k_group2<<<NWG2, 512, 0, stream>>>(row, col, vals, cnt, boff,
                                               (uint2*)d_out, E, N, nbuck2);
            k_place2<<<nbuck2, 512, 0, stream>>>((const uint2*)d_out, boff,
                                                 rowptr, rec, E, N, nbuck2);
        } else {
            // -- legacy atomic scatter (handles N > 131072) --
            k_prep<<<D, D, 0, stream>>>(W, w1, w2, M1T, M2T);
            k_cvt<<<(nquads + 255) / 256, 256, 0, stream>>>((const float4*)ego,
                                                            (uint2*)egob, nquads);
            hipMemsetAsync(deg, 0, (size_t)N * 4, stream);
            int nb = (N + 1023) / 1024;
            k_hist<<<(E + 255) / 256, 256, 0, stream>>>(row, deg, E, N);
            k_scan1<<<nb, 1024, 0, stream>>>(deg, rowptr, bsum, N);
            k_scan2<<<1, 1, 0, stream>>>(bsum, boff, nb, rowptr, N);
            k_scan3<<<nb, 1024, 0, stream>>>(deg, boff, rowptr, wp, N);
            k_scatter<<<(E + 255) / 256, 256, 0, stream>>>(row, col, vals, wp,
                                                           rec, E, N);
        }
        int nblocks = (N + 15) / 16;
        k_fused<<<nblocks, 256, 0, stream>>>(rowptr, rec, egob,
                                             (const float2*)ego, (const float2*)h0,
                                             M1T, M2T, b1, b2, (float*)d_out, N);
    } else {
        k_prep<<<D, D, 0, stream>>>(W, w1, w2, M1T, M2T);
        hipMemsetAsync(d_out, 0, (size_t)out_size * 4, stream);
        long long tthr = (long long)E * 64;
        int blocks = (int)((tthr + 255) / 256);
        k_coo_side<<<blocks, 256, 0, stream>>>(row, col, vals, (const float2*)ego,
                                               (float*)d_out, E, N);
        int nblocks = (N + 15) / 16;
        k_fused2<<<nblocks, 256, 0, stream>>>((const float2*)ego, (const float2*)h0,
                                              M1T, M2T, b1, b2, (float*)d_out, N);
    }
}